// Round 11
// baseline (709.178 us; speedup 1.0000x reference)
//
#include <hip/hip_runtime.h>

#define DIM 128
#define CHUNK 4096
#define PAIRC 4096
#define SENT 0xFFFFFFFFu
#define STAGECAP 9984   // CHUNK + 391*15 = 9961
typedef unsigned short ushort_t;
typedef short bf16x8 __attribute__((ext_vector_type(8)));
typedef float f32x4 __attribute__((ext_vector_type(4)));

__device__ inline ushort_t f2bf(float f) {
    unsigned int u = __float_as_uint(f);
    unsigned int r = (u + 0x7FFFu + ((u >> 16) & 1u)) >> 16;
    return (ushort_t)r;
}
__device__ inline unsigned int pack2bf(float lo, float hi) {
    return (unsigned int)f2bf(lo) | ((unsigned int)f2bf(hi) << 16);
}
__device__ inline float bflo2f(unsigned int u) { return __uint_as_float(u << 16); }
__device__ inline float bfhi2f(unsigned int u) { return __uint_as_float(u & 0xFFFF0000u); }

// ---------------------------------------------------------------------------
__global__ void f32_to_bf16_2_kernel(const float* __restrict__ a, const float* __restrict__ b,
                                     ushort_t* __restrict__ oa, ushort_t* __restrict__ ob, int n4) {
    const float* __restrict__ in = blockIdx.y ? b : a;
    ushort_t* __restrict__ out = blockIdx.y ? ob : oa;
    int i = blockIdx.x * blockDim.x + threadIdx.x;
    int stride = gridDim.x * blockDim.x;
    for (; i < n4; i += stride) {
        float4 v = *reinterpret_cast<const float4*>(in + (size_t)i * 4);
        ushort_t o[4] = {f2bf(v.x), f2bf(v.y), f2bf(v.z), f2bf(v.w)};
        *reinterpret_cast<uint2*>(out + (size_t)i * 4) = *reinterpret_cast<uint2*>(o);
    }
}

struct WPack { const float* Wl[4]; const float* Wr[4]; };

__global__ void pack_weights4_kernel(WPack wp, ushort_t* __restrict__ Wcat) {
    int l = blockIdx.y, j = blockIdx.x, k = threadIdx.x;
    float v = (k < DIM) ? wp.Wl[l][j * DIM + k] : wp.Wr[l][j * DIM + (k - DIM)];
    Wcat[l * 32768 + j * 256 + k] = f2bf(v);
}

// ---------------------------------------------------------------------------
__global__ void precompute_v_kernel(const float* __restrict__ outW0,
                                    const float* __restrict__ outW1,
                                    const float* __restrict__ outb0,
                                    const float* __restrict__ outb1,
                                    const float* __restrict__ regW,
                                    const float* __restrict__ regb,
                                    float* __restrict__ vbuf) {
    int t = threadIdx.x;
    if (t < DIM) {
        float s = 0.f;
        #pragma unroll 8
        for (int j = 0; j < DIM; ++j) s = fmaf(outW0[j * DIM + t], regW[j], s);
        vbuf[t] = s;
    } else {
        int k = t - DIM;
        float s = 0.f;
        #pragma unroll 8
        for (int j = 0; j < DIM; ++j) s = fmaf(outW1[j * DIM + k], regW[DIM + j], s);
        vbuf[t] = s;
    }
    if (t == 0) {
        float c = regb[0];
        for (int j = 0; j < DIM; ++j) c += outb0[j] * regW[j] + outb1[j] * regW[DIM + j];
        vbuf[2 * DIM] = c;
    }
}

// ---------------------------------------------------------------------------
// CSR build. pairs PACKED: (src<<8)|(dst&255), padded to 16-entry (64B) units.
// ---------------------------------------------------------------------------
struct EdgePtrs { const int* e[4]; };

__global__ void bin4_stage_kernel(EdgePtrs eps, int nedges, int* __restrict__ bpad,
                                  int* __restrict__ breal,
                                  unsigned int* __restrict__ pairs, int nbuck) {
    int list = blockIdx.y;
    const int* __restrict__ src = eps.e[list];
    const int* __restrict__ dst = eps.e[list] + nedges;
    __shared__ int cnt[512], loff[512], goff[512];
    __shared__ int wsum[4];
    __shared__ unsigned int stage[STAGECAP];
    const int tid = threadIdx.x;
    const int lane = tid & 63, w = tid >> 6;
    const int base = blockIdx.x * CHUNK;

    for (int b = tid; b < 512; b += 256) cnt[b] = 0;
    __syncthreads();

    // phase 1: count buckets
    int dstv[CHUNK / 256];
    #pragma unroll
    for (int it = 0; it < CHUNK / 256; ++it) {
        int e = base + it * 256 + tid;
        int d = (e < nedges) ? dst[e] : -1;
        dstv[it] = d;
        if (d >= 0) atomicAdd(&cnt[d >> 8], 1);
    }
    __syncthreads();

    // phase 2a: exclusive scan of padded sizes -> loff (2 buckets/thread)
    {
        int b0 = tid * 2, b1 = b0 + 1;
        int r0 = (cnt[b0] + 15) & ~15;
        int r1 = (cnt[b1] + 15) & ~15;
        int s = r0 + r1;
        int sv = s;
        #pragma unroll
        for (int off = 1; off < 64; off <<= 1) {
            int u = __shfl_up(sv, off);
            if (lane >= off) sv += u;
        }
        if (lane == 63) wsum[w] = sv;
        __syncthreads();
        int bw = 0;
        #pragma unroll
        for (int k = 0; k < 4; ++k)
            if (k < w) bw += wsum[k];
        int ex = bw + sv - s;
        loff[b0] = ex;
        loff[b1] = ex + r0;
    }
    // phase 2b: reserve global space per bucket; switch cnt to rank counter
    for (int b = tid; b < nbuck; b += 256) {
        int c = cnt[b];
        int res = (c + 15) & ~15;
        if (res > 0) {
            goff[b] = atomicAdd(&bpad[list * nbuck + b], res);
            atomicAdd(&breal[list * nbuck + b], c);
        }
        cnt[b] = 0;
    }
    __syncthreads();

    // phase 3: scatter pairs into LDS stage (cnt returns to real count)
    #pragma unroll
    for (int it = 0; it < CHUNK / 256; ++it) {
        int d = dstv[it];
        if (d >= 0) {
            int e = base + it * 256 + tid;
            int r = atomicAdd(&cnt[d >> 8], 1);
            stage[loff[d >> 8] + r] = ((unsigned int)src[e] << 8) | (unsigned int)(d & 255);
        }
    }
    __syncthreads();

    // phase 4: burst copy-out, one bucket per wave iteration (sentinel tail inline)
    for (int b = w; b < nbuck; b += 4) {
        int c = cnt[b];
        int res = (c + 15) & ~15;
        if (res == 0) continue;
        size_t go = ((size_t)list * nbuck + b) * PAIRC + goff[b];
        int lo = loff[b];
        for (int i = lane; i < res; i += 64)
            pairs[go + i] = (i < c) ? stage[lo + i] : SENT;
    }
}

// single block, 512 threads, 4 elems/thread; n = 4*nbuck <= 2048 (scans breal)
__global__ void bucket_scan_kernel(const int* __restrict__ breal, int* __restrict__ bbase,
                                   int n, int* __restrict__ rowptr, int n4, int total) {
    int t = threadIdx.x;
    int loc[4];
    int s = 0;
    #pragma unroll
    for (int k = 0; k < 4; ++k) {
        int i = t * 4 + k;
        loc[k] = (i < n) ? breal[i] : 0;
        s += loc[k];
    }
    int lane = t & 63, w = t >> 6;
    int sv = s;
    #pragma unroll
    for (int off = 1; off < 64; off <<= 1) {
        int u = __shfl_up(sv, off);
        if (lane >= off) sv += u;
    }
    __shared__ int wsum[8];
    if (lane == 63) wsum[w] = sv;
    __syncthreads();
    int base = 0;
    #pragma unroll
    for (int k = 0; k < 8; ++k)
        if (k < w) base += wsum[k];
    int ex = base + sv - s;
    #pragma unroll
    for (int k = 0; k < 4; ++k) {
        int i = t * 4 + k;
        if (i < n) bbase[i] = ex;
        ex += loc[k];
    }
    if (t == 0) rowptr[n4] = total;
}

// one block per (bucket, list)
__global__ void fillb_kernel(const unsigned int* __restrict__ pairs, const int* __restrict__ bpad,
                             const int* __restrict__ bbase, int* __restrict__ rowptr,
                             int* __restrict__ eidx, int N, int nbuck) {
    int list = blockIdx.y;
    int b = blockIdx.x;
    int d0 = b << 8;
    if (d0 >= N) return;
    int nd = N - d0; if (nd > 256) nd = 256;
    int slot = list * nbuck + b;
    int cntp = bpad[slot];
    int base = bbase[slot];
    const unsigned int* __restrict__ ps = pairs + (size_t)slot * PAIRC;

    __shared__ int h[256], cur[256];
    int t = threadIdx.x;
    h[t] = 0;
    __syncthreads();
    for (int i = t; i < cntp; i += 256) {
        unsigned int p = ps[i];
        if (p != SENT) atomicAdd(&h[p & 255u], 1);
    }
    __syncthreads();
    int v = h[t];
    int lane = t & 63, w = t >> 6;
    int sv = v;
    #pragma unroll
    for (int off = 1; off < 64; off <<= 1) {
        int u = __shfl_up(sv, off);
        if (lane >= off) sv += u;
    }
    __shared__ int wsum[4];
    if (lane == 63) wsum[w] = sv;
    __syncthreads();
    int wbase = 0;
    #pragma unroll
    for (int k = 0; k < 4; ++k)
        if (k < w) wbase += wsum[k];
    int ex = wbase + sv - v;
    if (t < nd) rowptr[(size_t)list * N + d0 + t] = base + ex;
    cur[t] = ex;
    __syncthreads();
    for (int i = t; i < cntp; i += 256) {
        unsigned int p = ps[i];
        if (p != SENT) {
            int ld = (int)(p & 255u);
            int r = atomicAdd(&cur[ld], 1);
            eidx[base + r] = (int)(p >> 8);
        }
    }
}

// ---------------------------------------------------------------------------
// FUSED aggregate + SAGE hop GEMM.
// Phase A: each block gather-means its 128 rows into LDS Am[128][136] (bf16).
// Phase B: h = relu([mean | xdst] @ Wcat^T + bl); A-frags for K<128 read
//          directly from Am; K>=128 staged from xdst (coalesced).
// MODE 0: H=bf16(h). MODE 1: out = c + dot(h,v). MODE 2: out += dot(h,v).
// ---------------------------------------------------------------------------
template <int MODE>
__launch_bounds__(256, 2)
__global__ void sage_fused(const ushort_t* __restrict__ xsrc,
                           const ushort_t* __restrict__ xdst,
                           const int* __restrict__ rowptr,
                           const int* __restrict__ eidx,
                           const ushort_t* __restrict__ Wcat,
                           const float* __restrict__ bl,
                           ushort_t* __restrict__ H,
                           const float* __restrict__ v,
                           const float* __restrict__ cptr,
                           float* __restrict__ out,
                           int nrows) {
    __shared__ ushort_t Am[128][136];  // mean tile (pad 8: stride 68 dw -> 2-way max)
    __shared__ ushort_t As[128][40];   // xdst k-tile staging
    __shared__ ushort_t Bs[128][40];
    __shared__ float red[2][128];

    const int tid = threadIdx.x;
    const int lane = tid & 63;
    const int w = tid >> 6;
    const int wr = w >> 1, wc = w & 1;
    const int lr = lane & 15;
    const int lk = (lane >> 4) * 8;
    const int row0 = blockIdx.x * 128;

    // ---- Phase A: gather-mean 32 rows per wave ----
    {
        const int sub = lane >> 4;
        // wave-wide rowptr prefetch: lanes 0..32 hold rowptr for rows w*32 .. w*32+32
        int rpv = 0;
        {
            int ridx = row0 + w * 32 + lane;
            if (lane <= 32) rpv = rowptr[ridx <= nrows ? ridx : nrows];
        }
        for (int i = 0; i < 32; ++i) {
            int rl = w * 32 + i;
            int r = row0 + rl;
            int beg = __shfl(rpv, i);
            int end = __shfl(rpv, i + 1);
            float a[8] = {0.f, 0.f, 0.f, 0.f, 0.f, 0.f, 0.f, 0.f};
            int deg = 0;
            if (r < nrows) {
                deg = end - beg;
                int nit = (deg + 3) >> 2;
                for (int it = 0; it < nit; ++it) {
                    int j = beg + it * 4 + sub;
                    if (j < end) {
                        int s = eidx[j];
                        uint4 u = *reinterpret_cast<const uint4*>(xsrc + (size_t)s * DIM + lr * 8);
                        a[0] += bflo2f(u.x); a[1] += bfhi2f(u.x);
                        a[2] += bflo2f(u.y); a[3] += bfhi2f(u.y);
                        a[4] += bflo2f(u.z); a[5] += bfhi2f(u.z);
                        a[6] += bflo2f(u.w); a[7] += bfhi2f(u.w);
                    }
                }
            }
            #pragma unroll
            for (int k = 0; k < 8; ++k) {
                a[k] += __shfl_xor(a[k], 16);
                a[k] += __shfl_xor(a[k], 32);
            }
            if (sub == 0) {
                float sc = 1.0f / fmaxf((float)deg, 1.0f);
                uint4 o;
                o.x = pack2bf(a[0] * sc, a[1] * sc);
                o.y = pack2bf(a[2] * sc, a[3] * sc);
                o.z = pack2bf(a[4] * sc, a[5] * sc);
                o.w = pack2bf(a[6] * sc, a[7] * sc);
                *reinterpret_cast<uint4*>(&Am[rl][lr * 8]) = o;
            }
        }
    }
    __syncthreads();

    // ---- Phase B: GEMM ----
    f32x4 acc[4][4];
    #pragma unroll
    for (int m = 0; m < 4; ++m)
        #pragma unroll
        for (int n = 0; n < 4; ++n)
            acc[m][n] = (f32x4){0.f, 0.f, 0.f, 0.f};

    for (int kt = 0; kt < 8; ++kt) {
        const int kb = kt * 32;
        const bool fromLds = (kt < 4);
        const int kbb = kb & (DIM - 1);

        if (!fromLds) {
            // stage xdst tile
            #pragma unroll
            for (int p = 0; p < 2; ++p) {
                int idx = p * 256 + tid;
                int r = idx >> 2, c = idx & 3;
                int grow = row0 + r;
                uint4 val = make_uint4(0u, 0u, 0u, 0u);
                if (grow < nrows)
                    val = *reinterpret_cast<const uint4*>(xdst + (size_t)grow * DIM + kbb + c * 8);
                *reinterpret_cast<uint4*>(&As[r][c * 8]) = val;
            }
        }
        #pragma unroll
        for (int p = 0; p < 2; ++p) {
            int idx = p * 256 + tid;
            int j = idx >> 2, c = idx & 3;
            uint4 val = *reinterpret_cast<const uint4*>(Wcat + j * 256 + kb + c * 8);
            *reinterpret_cast<uint4*>(&Bs[j][c * 8]) = val;
        }
        __syncthreads();

        bf16x8 af[4], bfm[4];
        #pragma unroll
        for (int m = 0; m < 4; ++m) {
            int row = wr * 64 + m * 16 + lr;
            af[m] = fromLds ? *reinterpret_cast<const bf16x8*>(&Am[row][kbb + lk])
                            : *reinterpret_cast<const bf16x8*>(&As[row][lk]);
        }
        #pragma unroll
        for (int n = 0; n < 4; ++n)
            bfm[n] = *reinterpret_cast<const bf16x8*>(&Bs[wc * 64 + n * 16 + lr][lk]);
        #pragma unroll
        for (int m = 0; m < 4; ++m)
            #pragma unroll
            for (int n = 0; n < 4; ++n)
                acc[m][n] = __builtin_amdgcn_mfma_f32_16x16x32_bf16(af[m], bfm[n], acc[m][n], 0, 0, 0);
        __syncthreads();
    }

    if (MODE == 0) {
        float blc[4];
        #pragma unroll
        for (int n = 0; n < 4; ++n) blc[n] = bl[wc * 64 + n * 16 + lr];
        #pragma unroll
        for (int m = 0; m < 4; ++m) {
            #pragma unroll
            for (int reg = 0; reg < 4; ++reg) {
                int row = row0 + wr * 64 + m * 16 + (lane >> 4) * 4 + reg;
                if (row < nrows) {
                    #pragma unroll
                    for (int n = 0; n < 4; ++n) {
                        int col = wc * 64 + n * 16 + lr;
                        H[(size_t)row * DIM + col] = f2bf(fmaxf(acc[m][n][reg] + blc[n], 0.f));
                    }
                }
            }
        }
    } else {
        float blc[4], vc[4];
        #pragma unroll
        for (int n = 0; n < 4; ++n) {
            int col = wc * 64 + n * 16 + lr;
            blc[n] = bl[col];
            vc[n] = v[col];
        }
        #pragma unroll
        for (int m = 0; m < 4; ++m) {
            float rp[4] = {0.f, 0.f, 0.f, 0.f};
            #pragma unroll
            for (int n = 0; n < 4; ++n)
                #pragma unroll
                for (int reg = 0; reg < 4; ++reg)
                    rp[reg] = fmaf(fmaxf(acc[m][n][reg] + blc[n], 0.f), vc[n], rp[reg]);
            #pragma unroll
            for (int reg = 0; reg < 4; ++reg) {
                float p = rp[reg];
                p += __shfl_xor(p, 1);
                p += __shfl_xor(p, 2);
                p += __shfl_xor(p, 4);
                p += __shfl_xor(p, 8);
                if (lr == 0)
                    red[wc][wr * 64 + m * 16 + (lane >> 4) * 4 + reg] = p;
            }
        }
        __syncthreads();
        if (tid < 128) {
            int row = row0 + tid;
            if (row < nrows) {
                float s = red[0][tid] + red[1][tid];
                if (MODE == 1) out[row] = cptr[0] + s;
                else out[row] += s;
            }
        }
    }
}

// ---------------------------------------------------------------------------
extern "C" void kernel_launch(void* const* d_in, const int* in_sizes, int n_in,
                              void* d_out, int out_size, void* d_ws, size_t ws_size,
                              hipStream_t stream) {
    const float* x_user = (const float*)d_in[0];
    const float* x_item = (const float*)d_in[1];
    const int* ei_m0_h0 = (const int*)d_in[2];
    const int* ei_m0_h1 = (const int*)d_in[3];
    const int* ei_m1_h0 = (const int*)d_in[4];
    const int* ei_m1_h1 = (const int*)d_in[5];
    const float* Wl00 = (const float*)d_in[6];
    const float* Wr00 = (const float*)d_in[7];
    const float* Wl01 = (const float*)d_in[8];
    const float* Wr01 = (const float*)d_in[9];
    const float* Wl10 = (const float*)d_in[10];
    const float* Wr10 = (const float*)d_in[11];
    const float* Wl11 = (const float*)d_in[12];
    const float* Wr11 = (const float*)d_in[13];
    const float* outW0 = (const float*)d_in[14];
    const float* outW1 = (const float*)d_in[15];
    const float* bl00 = (const float*)d_in[16];
    const float* bl01 = (const float*)d_in[17];
    const float* bl10 = (const float*)d_in[18];
    const float* bl11 = (const float*)d_in[19];
    const float* outb0 = (const float*)d_in[20];
    const float* outb1 = (const float*)d_in[21];
    const float* regW = (const float*)d_in[22];
    const float* regb = (const float*)d_in[23];

    const int N = in_sizes[0] / DIM;
    const int E = in_sizes[2] / 2;
    float* out = (float*)d_out;

    // ws: xbu | xbi | hibRegion (max(hib, pairs)) | Wcat | vbuf |
    //     bpad | breal | bbase | rowptr[4N+1] | eidx[4E]
    // pairs (25.63MB) aliases hibRegion: pairs die at fillb; hib first
    // written by hop0's MODE0 GEMM (stream-ordered, safe).
    const int n4 = 4 * N;
    const int nbuck = (N + 255) >> 8;
    const size_t hibElems = (size_t)N * DIM;
    const size_t pairElems = (size_t)4 * nbuck * PAIRC;          // uint
    const size_t regionShorts = (pairElems * 2 > hibElems) ? pairElems * 2 : hibElems;
    ushort_t* xbu = (ushort_t*)d_ws;
    ushort_t* xbi = xbu + hibElems;
    ushort_t* hib = xbi + hibElems;
    unsigned int* pairs = (unsigned int*)hib;
    ushort_t* Wcat = hib + regionShorts;
    float* vbuf = (float*)(Wcat + 4 * 32768);
    int* bpad = (int*)(vbuf + 2 * DIM + 1);
    int* breal = bpad + 4 * nbuck;
    int* bbase = breal + 4 * nbuck;
    int* rowptr = bbase + 4 * nbuck;
    int* eidx = rowptr + n4 + 1;

    // one-time conversions
    f32_to_bf16_2_kernel<<<dim3(1024, 2), 256, 0, stream>>>(x_user, x_item, xbu, xbi, N * DIM / 4);
    WPack wp;
    wp.Wl[0] = Wl00; wp.Wl[1] = Wl01; wp.Wl[2] = Wl10; wp.Wl[3] = Wl11;
    wp.Wr[0] = Wr00; wp.Wr[1] = Wr01; wp.Wr[2] = Wr10; wp.Wr[3] = Wr11;
    pack_weights4_kernel<<<dim3(128, 4), 256, 0, stream>>>(wp, Wcat);
    precompute_v_kernel<<<1, 256, 0, stream>>>(outW0, outW1, outb0, outb1, regW, regb, vbuf);

    // CSR build
    EdgePtrs eps;
    eps.e[0] = ei_m0_h0; eps.e[1] = ei_m0_h1; eps.e[2] = ei_m1_h0; eps.e[3] = ei_m1_h1;
    hipMemsetAsync(bpad, 0, (size_t)8 * nbuck * sizeof(int), stream);
    bin4_stage_kernel<<<dim3((E + CHUNK - 1) / CHUNK, 4), 256, 0, stream>>>(eps, E, bpad, breal, pairs, nbuck);
    bucket_scan_kernel<<<1, 512, 0, stream>>>(breal, bbase, 4 * nbuck, rowptr, n4, 4 * E);
    fillb_kernel<<<dim3(nbuck, 4), 256, 0, stream>>>(pairs, bpad, bbase, rowptr, eidx, N, nbuck);

    const int gemmBlocks = (N + 127) / 128;

    struct Hop {
        const ushort_t* xsrc;
        const ushort_t* xdst;
        const ushort_t* W;
        const float* bl;
        int mode;
        const float* v;
    };
    const Hop hops[4] = {
        {xbu, xbi, Wcat + 0 * 32768, bl00, 0, nullptr},
        {hib, xbu, Wcat + 1 * 32768, bl01, 1, vbuf},
        {xbu, xbi, Wcat + 2 * 32768, bl10, 0, nullptr},
        {hib, xbu, Wcat + 3 * 32768, bl11, 2, vbuf + DIM},
    };

    for (int h = 0; h < 4; ++h) {
        const Hop& hp = hops[h];
        const int* rp = rowptr + (size_t)h * N;
        if (hp.mode == 0)
            sage_fused<0><<<gemmBlocks, 256, 0, stream>>>(hp.xsrc, hp.xdst, rp, eidx, hp.W, hp.bl,
                                                          hib, nullptr, nullptr, nullptr, N);
        else if (hp.mode == 1)
            sage_fused<1><<<gemmBlocks, 256, 0, stream>>>(hp.xsrc, hp.xdst, rp, eidx, hp.W, hp.bl,
                                                          nullptr, hp.v, vbuf + 2 * DIM, out, N);
        else
            sage_fused<2><<<gemmBlocks, 256, 0, stream>>>(hp.xsrc, hp.xdst, rp, eidx, hp.W, hp.bl,
                                                          nullptr, hp.v, vbuf + 2 * DIM, out, N);
    }
}

// Round 12
// 395.967 us; speedup vs baseline: 1.7910x; 1.7910x over previous
//
#include <hip/hip_runtime.h>

#define DIM 128
#define CHUNK 4096
#define PAIRC 4096
#define SENT 0xFFFFFFFFu
#define STAGECAP 9984   // CHUNK + 391*15 = 9961
typedef unsigned short ushort_t;
typedef short bf16x8 __attribute__((ext_vector_type(8)));
typedef float f32x4 __attribute__((ext_vector_type(4)));

__device__ inline ushort_t f2bf(float f) {
    unsigned int u = __float_as_uint(f);
    unsigned int r = (u + 0x7FFFu + ((u >> 16) & 1u)) >> 16;
    return (ushort_t)r;
}
__device__ inline unsigned int pack2bf(float lo, float hi) {
    return (unsigned int)f2bf(lo) | ((unsigned int)f2bf(hi) << 16);
}
__device__ inline float bflo2f(unsigned int u) { return __uint_as_float(u << 16); }
__device__ inline float bfhi2f(unsigned int u) { return __uint_as_float(u & 0xFFFF0000u); }

// ---------------------------------------------------------------------------
__global__ void f32_to_bf16_2_kernel(const float* __restrict__ a, const float* __restrict__ b,
                                     ushort_t* __restrict__ oa, ushort_t* __restrict__ ob, int n4) {
    const float* __restrict__ in = blockIdx.y ? b : a;
    ushort_t* __restrict__ out = blockIdx.y ? ob : oa;
    int i = blockIdx.x * blockDim.x + threadIdx.x;
    int stride = gridDim.x * blockDim.x;
    for (; i < n4; i += stride) {
        float4 v = *reinterpret_cast<const float4*>(in + (size_t)i * 4);
        ushort_t o[4] = {f2bf(v.x), f2bf(v.y), f2bf(v.z), f2bf(v.w)};
        *reinterpret_cast<uint2*>(out + (size_t)i * 4) = *reinterpret_cast<uint2*>(o);
    }
}

struct WPack { const float* Wl[4]; const float* Wr[4]; };

__global__ void pack_weights4_kernel(WPack wp, ushort_t* __restrict__ Wcat) {
    int l = blockIdx.y, j = blockIdx.x, k = threadIdx.x;
    float v = (k < DIM) ? wp.Wl[l][j * DIM + k] : wp.Wr[l][j * DIM + (k - DIM)];
    Wcat[l * 32768 + j * 256 + k] = f2bf(v);
}

// ---------------------------------------------------------------------------
__global__ void precompute_v_kernel(const float* __restrict__ outW0,
                                    const float* __restrict__ outW1,
                                    const float* __restrict__ outb0,
                                    const float* __restrict__ outb1,
                                    const float* __restrict__ regW,
                                    const float* __restrict__ regb,
                                    float* __restrict__ vbuf) {
    int t = threadIdx.x;
    if (t < DIM) {
        float s = 0.f;
        #pragma unroll 8
        for (int j = 0; j < DIM; ++j) s = fmaf(outW0[j * DIM + t], regW[j], s);
        vbuf[t] = s;
    } else {
        int k = t - DIM;
        float s = 0.f;
        #pragma unroll 8
        for (int j = 0; j < DIM; ++j) s = fmaf(outW1[j * DIM + k], regW[DIM + j], s);
        vbuf[t] = s;
    }
    if (t == 0) {
        float c = regb[0];
        for (int j = 0; j < DIM; ++j) c += outb0[j] * regW[j] + outb1[j] * regW[DIM + j];
        vbuf[2 * DIM] = c;
    }
}

// ---------------------------------------------------------------------------
// CSR build. pairs PACKED: (src<<8)|(dst&255), padded to 16-entry (64B) units.
// bin4_stage: bin the chunk in LDS, then write each bucket region as FULL
// coalesced 64-lane bursts (single-writer lines -> no write amplification).
// ---------------------------------------------------------------------------
struct EdgePtrs { const int* e[4]; };

__global__ void bin4_stage_kernel(EdgePtrs eps, int nedges, int* __restrict__ bpad,
                                  int* __restrict__ breal,
                                  unsigned int* __restrict__ pairs, int nbuck) {
    int list = blockIdx.y;
    const int* __restrict__ src = eps.e[list];
    const int* __restrict__ dst = eps.e[list] + nedges;
    __shared__ int cnt[512], loff[512], goff[512];
    __shared__ int wsum[4];
    __shared__ unsigned int stage[STAGECAP];
    const int tid = threadIdx.x;
    const int lane = tid & 63, w = tid >> 6;
    const int base = blockIdx.x * CHUNK;

    for (int b = tid; b < 512; b += 256) cnt[b] = 0;
    __syncthreads();

    // phase 1: count buckets
    int dstv[CHUNK / 256];
    #pragma unroll
    for (int it = 0; it < CHUNK / 256; ++it) {
        int e = base + it * 256 + tid;
        int d = (e < nedges) ? dst[e] : -1;
        dstv[it] = d;
        if (d >= 0) atomicAdd(&cnt[d >> 8], 1);
    }
    __syncthreads();

    // phase 2a: exclusive scan of padded sizes -> loff (2 buckets/thread)
    {
        int b0 = tid * 2, b1 = b0 + 1;
        int r0 = (cnt[b0] + 15) & ~15;
        int r1 = (cnt[b1] + 15) & ~15;
        int s = r0 + r1;
        int sv = s;
        #pragma unroll
        for (int off = 1; off < 64; off <<= 1) {
            int u = __shfl_up(sv, off);
            if (lane >= off) sv += u;
        }
        if (lane == 63) wsum[w] = sv;
        __syncthreads();
        int bw = 0;
        #pragma unroll
        for (int k = 0; k < 4; ++k)
            if (k < w) bw += wsum[k];
        int ex = bw + sv - s;
        loff[b0] = ex;
        loff[b1] = ex + r0;
    }
    // phase 2b: reserve global space per bucket; switch cnt to rank counter
    for (int b = tid; b < nbuck; b += 256) {
        int c = cnt[b];
        int res = (c + 15) & ~15;
        if (res > 0) {
            goff[b] = atomicAdd(&bpad[list * nbuck + b], res);
            atomicAdd(&breal[list * nbuck + b], c);
        }
        cnt[b] = 0;
    }
    __syncthreads();

    // phase 3: scatter pairs into LDS stage (cnt returns to real count)
    #pragma unroll
    for (int it = 0; it < CHUNK / 256; ++it) {
        int d = dstv[it];
        if (d >= 0) {
            int e = base + it * 256 + tid;
            int r = atomicAdd(&cnt[d >> 8], 1);
            stage[loff[d >> 8] + r] = ((unsigned int)src[e] << 8) | (unsigned int)(d & 255);
        }
    }
    __syncthreads();

    // phase 4: burst copy-out, one bucket per wave iteration (sentinel tail inline)
    for (int b = w; b < nbuck; b += 4) {
        int c = cnt[b];
        int res = (c + 15) & ~15;
        if (res == 0) continue;
        size_t go = ((size_t)list * nbuck + b) * PAIRC + goff[b];
        int lo = loff[b];
        for (int i = lane; i < res; i += 64)
            pairs[go + i] = (i < c) ? stage[lo + i] : SENT;
    }
}

// single block, 512 threads, 4 elems/thread; n = 4*nbuck <= 2048 (scans breal)
__global__ void bucket_scan_kernel(const int* __restrict__ breal, int* __restrict__ bbase,
                                   int n, int* __restrict__ rowptr, int n4, int total) {
    int t = threadIdx.x;
    int loc[4];
    int s = 0;
    #pragma unroll
    for (int k = 0; k < 4; ++k) {
        int i = t * 4 + k;
        loc[k] = (i < n) ? breal[i] : 0;
        s += loc[k];
    }
    int lane = t & 63, w = t >> 6;
    int sv = s;
    #pragma unroll
    for (int off = 1; off < 64; off <<= 1) {
        int u = __shfl_up(sv, off);
        if (lane >= off) sv += u;
    }
    __shared__ int wsum[8];
    if (lane == 63) wsum[w] = sv;
    __syncthreads();
    int base = 0;
    #pragma unroll
    for (int k = 0; k < 8; ++k)
        if (k < w) base += wsum[k];
    int ex = base + sv - s;
    #pragma unroll
    for (int k = 0; k < 4; ++k) {
        int i = t * 4 + k;
        if (i < n) bbase[i] = ex;
        ex += loc[k];
    }
    if (t == 0) rowptr[n4] = total;
}

// one block per (bucket, list): skip sentinels, LDS histogram + scan,
// coalesced rowptr write, LDS-cursor placement into tight eidx region.
__global__ void fillb_kernel(const unsigned int* __restrict__ pairs, const int* __restrict__ bpad,
                             const int* __restrict__ bbase, int* __restrict__ rowptr,
                             int* __restrict__ eidx, int N, int nbuck) {
    int list = blockIdx.y;
    int b = blockIdx.x;
    int d0 = b << 8;
    if (d0 >= N) return;
    int nd = N - d0; if (nd > 256) nd = 256;
    int slot = list * nbuck + b;
    int cntp = bpad[slot];
    int base = bbase[slot];
    const unsigned int* __restrict__ ps = pairs + (size_t)slot * PAIRC;

    __shared__ int h[256], cur[256];
    int t = threadIdx.x;
    h[t] = 0;
    __syncthreads();
    for (int i = t; i < cntp; i += 256) {
        unsigned int p = ps[i];
        if (p != SENT) atomicAdd(&h[p & 255u], 1);
    }
    __syncthreads();
    int v = h[t];
    int lane = t & 63, w = t >> 6;
    int sv = v;
    #pragma unroll
    for (int off = 1; off < 64; off <<= 1) {
        int u = __shfl_up(sv, off);
        if (lane >= off) sv += u;
    }
    __shared__ int wsum[4];
    if (lane == 63) wsum[w] = sv;
    __syncthreads();
    int wbase = 0;
    #pragma unroll
    for (int k = 0; k < 4; ++k)
        if (k < w) wbase += wsum[k];
    int ex = wbase + sv - v;
    if (t < nd) rowptr[(size_t)list * N + d0 + t] = base + ex;
    cur[t] = ex;
    __syncthreads();
    for (int i = t; i < cntp; i += 256) {
        unsigned int p = ps[i];
        if (p != SENT) {
            int ld = (int)(p & 255u);
            int r = atomicAdd(&cur[ld], 1);
            eidx[base + r] = (int)(p >> 8);
        }
    }
}

// ---------------------------------------------------------------------------
// Gather-side mean, 4-edge MLP: one wave per row; sub-group s (16 lanes, uint4
// = 16B = 8 bf16 per lane) handles edges j = beg + it*4 + s. High-occupancy
// standalone kernel (latency-bound regime needs TLP — r11 fusion lesson).
// ---------------------------------------------------------------------------
__global__ void aggregate_kernel(const ushort_t* __restrict__ xsrc,
                                 const int* __restrict__ rowptr,
                                 const int* __restrict__ eidx,
                                 ushort_t* __restrict__ mean, int n) {
    int wid = (blockIdx.x * blockDim.x + threadIdx.x) >> 6;
    int lane = threadIdx.x & 63;
    int nw = (gridDim.x * blockDim.x) >> 6;
    const int sub = lane >> 4;
    const int lr = lane & 15;
    for (int r = wid; r < n; r += nw) {
        int beg = rowptr[r];
        int end = rowptr[r + 1];
        int deg = end - beg;
        float a[8] = {0.f, 0.f, 0.f, 0.f, 0.f, 0.f, 0.f, 0.f};
        int nit = (deg + 3) >> 2;
        for (int it = 0; it < nit; ++it) {
            int j = beg + it * 4 + sub;
            if (j < end) {
                int s = eidx[j];
                uint4 u = *reinterpret_cast<const uint4*>(xsrc + (size_t)s * DIM + lr * 8);
                a[0] += bflo2f(u.x); a[1] += bfhi2f(u.x);
                a[2] += bflo2f(u.y); a[3] += bfhi2f(u.y);
                a[4] += bflo2f(u.z); a[5] += bfhi2f(u.z);
                a[6] += bflo2f(u.w); a[7] += bfhi2f(u.w);
            }
        }
        #pragma unroll
        for (int k = 0; k < 8; ++k) {
            a[k] += __shfl_xor(a[k], 16);
            a[k] += __shfl_xor(a[k], 32);
        }
        if (sub == 0) {
            float sc = 1.0f / fmaxf((float)deg, 1.0f);
            uint4 o;
            o.x = pack2bf(a[0] * sc, a[1] * sc);
            o.y = pack2bf(a[2] * sc, a[3] * sc);
            o.z = pack2bf(a[4] * sc, a[5] * sc);
            o.w = pack2bf(a[6] * sc, a[7] * sc);
            *reinterpret_cast<uint4*>(mean + (size_t)r * DIM + lr * 8) = o;
        }
    }
}

// ---------------------------------------------------------------------------
// MFMA SAGE hop GEMM (bf16 in, f32 accum).
// ---------------------------------------------------------------------------
template <int MODE>
__launch_bounds__(256, 2)
__global__ void sage_gemm_mfma(const ushort_t* __restrict__ A0,
                               const ushort_t* __restrict__ A1,
                               const ushort_t* __restrict__ Wcat,
                               const float* __restrict__ bl,
                               ushort_t* __restrict__ H,
                               const float* __restrict__ v,
                               const float* __restrict__ cptr,
                               float* __restrict__ out,
                               int nrows) {
    __shared__ ushort_t As[128][40];
    __shared__ ushort_t Bs[128][40];
    __shared__ float red[2][128];

    const int tid = threadIdx.x;
    const int lane = tid & 63;
    const int w = tid >> 6;
    const int wr = w >> 1, wc = w & 1;
    const int lr = lane & 15;
    const int lk = (lane >> 4) * 8;
    const int row0 = blockIdx.x * 128;

    f32x4 acc[4][4];
    #pragma unroll
    for (int m = 0; m < 4; ++m)
        #pragma unroll
        for (int n = 0; n < 4; ++n)
            acc[m][n] = (f32x4){0.f, 0.f, 0.f, 0.f};

    for (int kt = 0; kt < 8; ++kt) {
        const int kb = kt * 32;
        const ushort_t* __restrict__ Asrc = (kb < DIM) ? A0 : A1;
        const int kbb = kb & (DIM - 1);

        #pragma unroll
        for (int p = 0; p < 2; ++p) {
            int idx = p * 256 + tid;
            int r = idx >> 2, c = idx & 3;
            int grow = row0 + r;
            uint4 val = make_uint4(0u, 0u, 0u, 0u);
            if (grow < nrows)
                val = *reinterpret_cast<const uint4*>(Asrc + (size_t)grow * DIM + kbb + c * 8);
            *reinterpret_cast<uint4*>(&As[r][c * 8]) = val;
        }
        #pragma unroll
        for (int p = 0; p < 2; ++p) {
            int idx = p * 256 + tid;
            int j = idx >> 2, c = idx & 3;
            uint4 val = *reinterpret_cast<const uint4*>(Wcat + j * 256 + kb + c * 8);
            *reinterpret_cast<uint4*>(&Bs[j][c * 8]) = val;
        }
        __syncthreads();

        bf16x8 af[4], bfm[4];
        #pragma unroll
        for (int m = 0; m < 4; ++m)
            af[m] = *reinterpret_cast<const bf16x8*>(&As[wr * 64 + m * 16 + lr][lk]);
        #pragma unroll
        for (int n = 0; n < 4; ++n)
            bfm[n] = *reinterpret_cast<const bf16x8*>(&Bs[wc * 64 + n * 16 + lr][lk]);
        #pragma unroll
        for (int m = 0; m < 4; ++m)
            #pragma unroll
            for (int n = 0; n < 4; ++n)
                acc[m][n] = __builtin_amdgcn_mfma_f32_16x16x32_bf16(af[m], bfm[n], acc[m][n], 0, 0, 0);
        __syncthreads();
    }

    if (MODE == 0) {
        float blc[4];
        #pragma unroll
        for (int n = 0; n < 4; ++n) blc[n] = bl[wc * 64 + n * 16 + lr];
        #pragma unroll
        for (int m = 0; m < 4; ++m) {
            #pragma unroll
            for (int reg = 0; reg < 4; ++reg) {
                int row = row0 + wr * 64 + m * 16 + (lane >> 4) * 4 + reg;
                if (row < nrows) {
                    #pragma unroll
                    for (int n = 0; n < 4; ++n) {
                        int col = wc * 64 + n * 16 + lr;
                        H[(size_t)row * DIM + col] = f2bf(fmaxf(acc[m][n][reg] + blc[n], 0.f));
                    }
                }
            }
        }
    } else {
        float blc[4], vc[4];
        #pragma unroll
        for (int n = 0; n < 4; ++n) {
            int col = wc * 64 + n * 16 + lr;
            blc[n] = bl[col];
            vc[n] = v[col];
        }
        #pragma unroll
        for (int m = 0; m < 4; ++m) {
            float rp[4] = {0.f, 0.f, 0.f, 0.f};
            #pragma unroll
            for (int n = 0; n < 4; ++n)
                #pragma unroll
                for (int reg = 0; reg < 4; ++reg)
                    rp[reg] = fmaf(fmaxf(acc[m][n][reg] + blc[n], 0.f), vc[n], rp[reg]);
            #pragma unroll
            for (int reg = 0; reg < 4; ++reg) {
                float p = rp[reg];
                p += __shfl_xor(p, 1);
                p += __shfl_xor(p, 2);
                p += __shfl_xor(p, 4);
                p += __shfl_xor(p, 8);
                if (lr == 0)
                    red[wc][wr * 64 + m * 16 + (lane >> 4) * 4 + reg] = p;
            }
        }
        __syncthreads();
        if (tid < 128) {
            int row = row0 + tid;
            if (row < nrows) {
                float s = red[0][tid] + red[1][tid];
                if (MODE == 1) out[row] = cptr[0] + s;
                else out[row] += s;
            }
        }
    }
}

// ---------------------------------------------------------------------------
extern "C" void kernel_launch(void* const* d_in, const int* in_sizes, int n_in,
                              void* d_out, int out_size, void* d_ws, size_t ws_size,
                              hipStream_t stream) {
    const float* x_user = (const float*)d_in[0];
    const float* x_item = (const float*)d_in[1];
    const int* ei_m0_h0 = (const int*)d_in[2];
    const int* ei_m0_h1 = (const int*)d_in[3];
    const int* ei_m1_h0 = (const int*)d_in[4];
    const int* ei_m1_h1 = (const int*)d_in[5];
    const float* Wl00 = (const float*)d_in[6];
    const float* Wr00 = (const float*)d_in[7];
    const float* Wl01 = (const float*)d_in[8];
    const float* Wr01 = (const float*)d_in[9];
    const float* Wl10 = (const float*)d_in[10];
    const float* Wr10 = (const float*)d_in[11];
    const float* Wl11 = (const float*)d_in[12];
    const float* Wr11 = (const float*)d_in[13];
    const float* outW0 = (const float*)d_in[14];
    const float* outW1 = (const float*)d_in[15];
    const float* bl00 = (const float*)d_in[16];
    const float* bl01 = (const float*)d_in[17];
    const float* bl10 = (const float*)d_in[18];
    const float* bl11 = (const float*)d_in[19];
    const float* outb0 = (const float*)d_in[20];
    const float* outb1 = (const float*)d_in[21];
    const float* regW = (const float*)d_in[22];
    const float* regb = (const float*)d_in[23];

    const int N = in_sizes[0] / DIM;
    const int E = in_sizes[2] / 2;
    float* out = (float*)d_out;

    // ws: xbu | xbi | meanb | hib (bf16 N*128 each) | Wcat | vbuf |
    //     bpad | breal | bbase | rowptr[4N+1] | eidx[4E]
    // pairs (uint, 4*nbuck*PAIRC*4B = 25.6MB) ALIASES meanb: pairs die at
    // fillb; meanb first written by hop0 aggregate (stream-ordered, safe).
    const int n4 = 4 * N;
    const int nbuck = (N + 255) >> 8;
    ushort_t* xbu = (ushort_t*)d_ws;
    ushort_t* xbi = xbu + (size_t)N * DIM;
    ushort_t* meanb = xbi + (size_t)N * DIM;
    ushort_t* hib = meanb + (size_t)N * DIM;
    unsigned int* pairs = (unsigned int*)meanb;
    ushort_t* Wcat = hib + (size_t)N * DIM;
    float* vbuf = (float*)(Wcat + 4 * 32768);
    int* bpad = (int*)(vbuf + 2 * DIM + 1);
    int* breal = bpad + 4 * nbuck;
    int* bbase = breal + 4 * nbuck;
    int* rowptr = bbase + 4 * nbuck;
    int* eidx = rowptr + n4 + 1;

    // one-time conversions (merged launches)
    f32_to_bf16_2_kernel<<<dim3(1024, 2), 256, 0, stream>>>(x_user, x_item, xbu, xbi, N * DIM / 4);
    WPack wp;
    wp.Wl[0] = Wl00; wp.Wl[1] = Wl01; wp.Wl[2] = Wl10; wp.Wl[3] = Wl11;
    wp.Wr[0] = Wr00; wp.Wr[1] = Wr01; wp.Wr[2] = Wr10; wp.Wr[3] = Wr11;
    pack_weights4_kernel<<<dim3(128, 4), 256, 0, stream>>>(wp, Wcat);
    precompute_v_kernel<<<1, 256, 0, stream>>>(outW0, outW1, outb0, outb1, regW, regb, vbuf);

    // CSR build
    EdgePtrs eps;
    eps.e[0] = ei_m0_h0; eps.e[1] = ei_m0_h1; eps.e[2] = ei_m1_h0; eps.e[3] = ei_m1_h1;
    hipMemsetAsync(bpad, 0, (size_t)8 * nbuck * sizeof(int), stream);
    bin4_stage_kernel<<<dim3((E + CHUNK - 1) / CHUNK, 4), 256, 0, stream>>>(eps, E, bpad, breal, pairs, nbuck);
    bucket_scan_kernel<<<1, 512, 0, stream>>>(breal, bbase, 4 * nbuck, rowptr, n4, 4 * E);
    fillb_kernel<<<dim3(nbuck, 4), 256, 0, stream>>>(pairs, bpad, bbase, rowptr, eidx, N, nbuck);

    const int gemmBlocks = (N + 127) / 128;
    const int aggBlocks = 2048;

    struct Hop {
        const ushort_t* xsrc;
        const ushort_t* xdst;
        const ushort_t* W;
        const float* bl;
        int mode;
        const float* v;
    };
    const Hop hops[4] = {
        {xbu, xbi, Wcat + 0 * 32768, bl00, 0, nullptr},
        {hib, xbu, Wcat + 1 * 32768, bl01, 1, vbuf},
        {xbu, xbi, Wcat + 2 * 32768, bl10, 0, nullptr},
        {hib, xbu, Wcat + 3 * 32768, bl11, 2, vbuf + DIM},
    };

    for (int h = 0; h < 4; ++h) {
        const Hop& hp = hops[h];
        aggregate_kernel<<<aggBlocks, 256, 0, stream>>>(hp.xsrc, rowptr + (size_t)h * N, eidx, meanb, N);
        if (hp.mode == 0)
            sage_gemm_mfma<0><<<gemmBlocks, 256, 0, stream>>>(meanb, hp.xdst, hp.W, hp.bl,
                                                              hib, nullptr, nullptr, nullptr, N);
        else if (hp.mode == 1)
            sage_gemm_mfma<1><<<gemmBlocks, 256, 0, stream>>>(meanb, hp.xdst, hp.W, hp.bl,
                                                              nullptr, hp.v, vbuf + 2 * DIM, out, N);
        else
            sage_gemm_mfma<2><<<gemmBlocks, 256, 0, stream>>>(meanb, hp.xdst, hp.W, hp.bl,
                                                              nullptr, hp.v, vbuf + 2 * DIM, out, N);
    }
}

// Round 13
// 351.422 us; speedup vs baseline: 2.0180x; 1.1268x over previous
//
#include <hip/hip_runtime.h>

#define DIM 128
#define CHUNK 8192
#define PAIRC 4096
#define SENT 0xFFFFFFFFu
#define STAGECAP 14080   // CHUNK + 391*15 = 14057
typedef unsigned short ushort_t;
typedef short bf16x8 __attribute__((ext_vector_type(8)));
typedef float f32x4 __attribute__((ext_vector_type(4)));

__device__ inline ushort_t f2bf(float f) {
    unsigned int u = __float_as_uint(f);
    unsigned int r = (u + 0x7FFFu + ((u >> 16) & 1u)) >> 16;
    return (ushort_t)r;
}
__device__ inline unsigned int pack2bf(float lo, float hi) {
    return (unsigned int)f2bf(lo) | ((unsigned int)f2bf(hi) << 16);
}
__device__ inline float bflo2f(unsigned int u) { return __uint_as_float(u << 16); }
__device__ inline float bfhi2f(unsigned int u) { return __uint_as_float(u & 0xFFFF0000u); }

// ---------------------------------------------------------------------------
__global__ void f32_to_bf16_2_kernel(const float* __restrict__ a, const float* __restrict__ b,
                                     ushort_t* __restrict__ oa, ushort_t* __restrict__ ob, int n4) {
    const float* __restrict__ in = blockIdx.y ? b : a;
    ushort_t* __restrict__ out = blockIdx.y ? ob : oa;
    int i = blockIdx.x * blockDim.x + threadIdx.x;
    int stride = gridDim.x * blockDim.x;
    for (; i < n4; i += stride) {
        float4 v = *reinterpret_cast<const float4*>(in + (size_t)i * 4);
        ushort_t o[4] = {f2bf(v.x), f2bf(v.y), f2bf(v.z), f2bf(v.w)};
        *reinterpret_cast<uint2*>(out + (size_t)i * 4) = *reinterpret_cast<uint2*>(o);
    }
}

struct WPack { const float* Wl[4]; const float* Wr[4]; };

__global__ void pack_weights4_kernel(WPack wp, ushort_t* __restrict__ Wcat) {
    int l = blockIdx.y, j = blockIdx.x, k = threadIdx.x;
    float v = (k < DIM) ? wp.Wl[l][j * DIM + k] : wp.Wr[l][j * DIM + (k - DIM)];
    Wcat[l * 32768 + j * 256 + k] = f2bf(v);
}

// ---------------------------------------------------------------------------
__global__ void precompute_v_kernel(const float* __restrict__ outW0,
                                    const float* __restrict__ outW1,
                                    const float* __restrict__ outb0,
                                    const float* __restrict__ outb1,
                                    const float* __restrict__ regW,
                                    const float* __restrict__ regb,
                                    float* __restrict__ vbuf) {
    int t = threadIdx.x;
    if (t < DIM) {
        float s = 0.f;
        #pragma unroll 8
        for (int j = 0; j < DIM; ++j) s = fmaf(outW0[j * DIM + t], regW[j], s);
        vbuf[t] = s;
    } else {
        int k = t - DIM;
        float s = 0.f;
        #pragma unroll 8
        for (int j = 0; j < DIM; ++j) s = fmaf(outW1[j * DIM + k], regW[DIM + j], s);
        vbuf[t] = s;
    }
    if (t == 0) {
        float c = regb[0];
        for (int j = 0; j < DIM; ++j) c += outb0[j] * regW[j] + outb1[j] * regW[DIM + j];
        vbuf[2 * DIM] = c;
    }
}

// ---------------------------------------------------------------------------
// CSR build. pairs PACKED: (src<<8)|(dst&255), padded to 16-entry (64B) units.
// bin4_stage (512 threads): bin the chunk in LDS, then write each bucket
// region as FULL coalesced 64-lane bursts (single-writer-instruction lines).
// ---------------------------------------------------------------------------
struct EdgePtrs { const int* e[4]; };

__global__ void bin4_stage_kernel(EdgePtrs eps, int nedges, int* __restrict__ bpad,
                                  int* __restrict__ breal,
                                  unsigned int* __restrict__ pairs, int nbuck) {
    int list = blockIdx.y;
    const int* __restrict__ src = eps.e[list];
    const int* __restrict__ dst = eps.e[list] + nedges;
    __shared__ int cnt[512], loff[512], goff[512];
    __shared__ int wsum[8];
    __shared__ unsigned int stage[STAGECAP];
    const int tid = threadIdx.x;          // 512 threads = 8 waves
    const int lane = tid & 63, w = tid >> 6;
    const int base = blockIdx.x * CHUNK;

    if (tid < 512) cnt[tid] = 0;
    __syncthreads();

    // phase 1: count buckets (16 edges/thread)
    int dstv[CHUNK / 512];
    #pragma unroll
    for (int it = 0; it < CHUNK / 512; ++it) {
        int e = base + it * 512 + tid;
        int d = (e < nedges) ? dst[e] : -1;
        dstv[it] = d;
        if (d >= 0) atomicAdd(&cnt[d >> 8], 1);
    }
    __syncthreads();

    // phase 2a: exclusive scan of padded sizes -> loff (1 bucket/thread)
    {
        int c = cnt[tid];
        int r = (c + 15) & ~15;
        int sv = r;
        #pragma unroll
        for (int off = 1; off < 64; off <<= 1) {
            int u = __shfl_up(sv, off);
            if (lane >= off) sv += u;
        }
        if (lane == 63) wsum[w] = sv;
        __syncthreads();
        int bw = 0;
        #pragma unroll
        for (int k = 0; k < 8; ++k)
            if (k < w) bw += wsum[k];
        loff[tid] = bw + sv - r;
    }
    __syncthreads();
    // phase 2b: reserve global space per bucket; switch cnt to rank counter
    if (tid < nbuck) {
        int c = cnt[tid];
        int res = (c + 15) & ~15;
        if (res > 0) {
            goff[tid] = atomicAdd(&bpad[list * nbuck + tid], res);
            atomicAdd(&breal[list * nbuck + tid], c);
        }
        cnt[tid] = 0;
    }
    __syncthreads();

    // phase 3: scatter pairs into LDS stage (cnt returns to real count)
    #pragma unroll
    for (int it = 0; it < CHUNK / 512; ++it) {
        int d = dstv[it];
        if (d >= 0) {
            int e = base + it * 512 + tid;
            int r = atomicAdd(&cnt[d >> 8], 1);
            stage[loff[d >> 8] + r] = ((unsigned int)src[e] << 8) | (unsigned int)(d & 255);
        }
    }
    __syncthreads();

    // phase 4: burst copy-out, one bucket per wave iteration (sentinel tail inline)
    for (int b = w; b < nbuck; b += 8) {
        int c = cnt[b];
        int res = (c + 15) & ~15;
        if (res == 0) continue;
        size_t go = ((size_t)list * nbuck + b) * PAIRC + goff[b];
        int lo = loff[b];
        for (int i = lane; i < res; i += 64)
            pairs[go + i] = (i < c) ? stage[lo + i] : SENT;
    }
}

// single block, 512 threads, 4 elems/thread; n = 4*nbuck <= 2048 (scans breal)
__global__ void bucket_scan_kernel(const int* __restrict__ breal, int* __restrict__ bbase,
                                   int n, int* __restrict__ rowptr, int n4, int total) {
    int t = threadIdx.x;
    int loc[4];
    int s = 0;
    #pragma unroll
    for (int k = 0; k < 4; ++k) {
        int i = t * 4 + k;
        loc[k] = (i < n) ? breal[i] : 0;
        s += loc[k];
    }
    int lane = t & 63, w = t >> 6;
    int sv = s;
    #pragma unroll
    for (int off = 1; off < 64; off <<= 1) {
        int u = __shfl_up(sv, off);
        if (lane >= off) sv += u;
    }
    __shared__ int wsum[8];
    if (lane == 63) wsum[w] = sv;
    __syncthreads();
    int base = 0;
    #pragma unroll
    for (int k = 0; k < 8; ++k)
        if (k < w) base += wsum[k];
    int ex = base + sv - s;
    #pragma unroll
    for (int k = 0; k < 4; ++k) {
        int i = t * 4 + k;
        if (i < n) bbase[i] = ex;
        ex += loc[k];
    }
    if (t == 0) rowptr[n4] = total;
}

// one block per (bucket, list): skip sentinels, LDS histogram + scan,
// coalesced rowptr write, LDS-cursor placement into tight eidx region.
__global__ void fillb_kernel(const unsigned int* __restrict__ pairs, const int* __restrict__ bpad,
                             const int* __restrict__ bbase, int* __restrict__ rowptr,
                             int* __restrict__ eidx, int N, int nbuck) {
    int list = blockIdx.y;
    int b = blockIdx.x;
    int d0 = b << 8;
    if (d0 >= N) return;
    int nd = N - d0; if (nd > 256) nd = 256;
    int slot = list * nbuck + b;
    int cntp = bpad[slot];
    int base = bbase[slot];
    const unsigned int* __restrict__ ps = pairs + (size_t)slot * PAIRC;

    __shared__ int h[256], cur[256];
    int t = threadIdx.x;
    h[t] = 0;
    __syncthreads();
    for (int i = t; i < cntp; i += 256) {
        unsigned int p = ps[i];
        if (p != SENT) atomicAdd(&h[p & 255u], 1);
    }
    __syncthreads();
    int v = h[t];
    int lane = t & 63, w = t >> 6;
    int sv = v;
    #pragma unroll
    for (int off = 1; off < 64; off <<= 1) {
        int u = __shfl_up(sv, off);
        if (lane >= off) sv += u;
    }
    __shared__ int wsum[4];
    if (lane == 63) wsum[w] = sv;
    __syncthreads();
    int wbase = 0;
    #pragma unroll
    for (int k = 0; k < 4; ++k)
        if (k < w) wbase += wsum[k];
    int ex = wbase + sv - v;
    if (t < nd) rowptr[(size_t)list * N + d0 + t] = base + ex;
    cur[t] = ex;
    __syncthreads();
    for (int i = t; i < cntp; i += 256) {
        unsigned int p = ps[i];
        if (p != SENT) {
            int ld = (int)(p & 255u);
            int r = atomicAdd(&cur[ld], 1);
            eidx[base + r] = (int)(p >> 8);
        }
    }
}

// ---------------------------------------------------------------------------
// Gather-side mean, 4-edge MLP: one wave per row; sub-group s (16 lanes, uint4
// = 16B = 8 bf16 per lane) handles edges j = beg + it*4 + s. High-occupancy
// standalone kernel (latency-bound regime needs TLP — r11 fusion lesson).
// ---------------------------------------------------------------------------
__global__ void aggregate_kernel(const ushort_t* __restrict__ xsrc,
                                 const int* __restrict__ rowptr,
                                 const int* __restrict__ eidx,
                                 ushort_t* __restrict__ mean, int n) {
    int wid = (blockIdx.x * blockDim.x + threadIdx.x) >> 6;
    int lane = threadIdx.x & 63;
    int nw = (gridDim.x * blockDim.x) >> 6;
    const int sub = lane >> 4;
    const int lr = lane & 15;
    for (int r = wid; r < n; r += nw) {
        int beg = rowptr[r];
        int end = rowptr[r + 1];
        int deg = end - beg;
        float a[8] = {0.f, 0.f, 0.f, 0.f, 0.f, 0.f, 0.f, 0.f};
        int nit = (deg + 3) >> 2;
        for (int it = 0; it < nit; ++it) {
            int j = beg + it * 4 + sub;
            if (j < end) {
                int s = eidx[j];
                uint4 u = *reinterpret_cast<const uint4*>(xsrc + (size_t)s * DIM + lr * 8);
                a[0] += bflo2f(u.x); a[1] += bfhi2f(u.x);
                a[2] += bflo2f(u.y); a[3] += bfhi2f(u.y);
                a[4] += bflo2f(u.z); a[5] += bfhi2f(u.z);
                a[6] += bflo2f(u.w); a[7] += bfhi2f(u.w);
            }
        }
        #pragma unroll
        for (int k = 0; k < 8; ++k) {
            a[k] += __shfl_xor(a[k], 16);
            a[k] += __shfl_xor(a[k], 32);
        }
        if (sub == 0) {
            float sc = 1.0f / fmaxf((float)deg, 1.0f);
            uint4 o;
            o.x = pack2bf(a[0] * sc, a[1] * sc);
            o.y = pack2bf(a[2] * sc, a[3] * sc);
            o.z = pack2bf(a[4] * sc, a[5] * sc);
            o.w = pack2bf(a[6] * sc, a[7] * sc);
            *reinterpret_cast<uint4*>(mean + (size_t)r * DIM + lr * 8) = o;
        }
    }
}

// ---------------------------------------------------------------------------
// MFMA SAGE hop GEMM (bf16 in, f32 accum).
// ---------------------------------------------------------------------------
template <int MODE>
__launch_bounds__(256, 2)
__global__ void sage_gemm_mfma(const ushort_t* __restrict__ A0,
                               const ushort_t* __restrict__ A1,
                               const ushort_t* __restrict__ Wcat,
                               const float* __restrict__ bl,
                               ushort_t* __restrict__ H,
                               const float* __restrict__ v,
                               const float* __restrict__ cptr,
                               float* __restrict__ out,
                               int nrows) {
    __shared__ ushort_t As[128][40];
    __shared__ ushort_t Bs[128][40];
    __shared__ float red[2][128];

    const int tid = threadIdx.x;
    const int lane = tid & 63;
    const int w = tid >> 6;
    const int wr = w >> 1, wc = w & 1;
    const int lr = lane & 15;
    const int lk = (lane >> 4) * 8;
    const int row0 = blockIdx.x * 128;

    f32x4 acc[4][4];
    #pragma unroll
    for (int m = 0; m < 4; ++m)
        #pragma unroll
        for (int n = 0; n < 4; ++n)
            acc[m][n] = (f32x4){0.f, 0.f, 0.f, 0.f};

    for (int kt = 0; kt < 8; ++kt) {
        const int kb = kt * 32;
        const ushort_t* __restrict__ Asrc = (kb < DIM) ? A0 : A1;
        const int kbb = kb & (DIM - 1);

        #pragma unroll
        for (int p = 0; p < 2; ++p) {
            int idx = p * 256 + tid;
            int r = idx >> 2, c = idx & 3;
            int grow = row0 + r;
            uint4 val = make_uint4(0u, 0u, 0u, 0u);
            if (grow < nrows)
                val = *reinterpret_cast<const uint4*>(Asrc + (size_t)grow * DIM + kbb + c * 8);
            *reinterpret_cast<uint4*>(&As[r][c * 8]) = val;
        }
        #pragma unroll
        for (int p = 0; p < 2; ++p) {
            int idx = p * 256 + tid;
            int j = idx >> 2, c = idx & 3;
            uint4 val = *reinterpret_cast<const uint4*>(Wcat + j * 256 + kb + c * 8);
            *reinterpret_cast<uint4*>(&Bs[j][c * 8]) = val;
        }
        __syncthreads();

        bf16x8 af[4], bfm[4];
        #pragma unroll
        for (int m = 0; m < 4; ++m)
            af[m] = *reinterpret_cast<const bf16x8*>(&As[wr * 64 + m * 16 + lr][lk]);
        #pragma unroll
        for (int n = 0; n < 4; ++n)
            bfm[n] = *reinterpret_cast<const bf16x8*>(&Bs[wc * 64 + n * 16 + lr][lk]);
        #pragma unroll
        for (int m = 0; m < 4; ++m)
            #pragma unroll
            for (int n = 0; n < 4; ++n)
                acc[m][n] = __builtin_amdgcn_mfma_f32_16x16x32_bf16(af[m], bfm[n], acc[m][n], 0, 0, 0);
        __syncthreads();
    }

    if (MODE == 0) {
        float blc[4];
        #pragma unroll
        for (int n = 0; n < 4; ++n) blc[n] = bl[wc * 64 + n * 16 + lr];
        #pragma unroll
        for (int m = 0; m < 4; ++m) {
            #pragma unroll
            for (int reg = 0; reg < 4; ++reg) {
                int row = row0 + wr * 64 + m * 16 + (lane >> 4) * 4 + reg;
                if (row < nrows) {
                    #pragma unroll
                    for (int n = 0; n < 4; ++n) {
                        int col = wc * 64 + n * 16 + lr;
                        H[(size_t)row * DIM + col] = f2bf(fmaxf(acc[m][n][reg] + blc[n], 0.f));
                    }
                }
            }
        }
    } else {
        float blc[4], vc[4];
        #pragma unroll
        for (int n = 0; n < 4; ++n) {
            int col = wc * 64 + n * 16 + lr;
            blc[n] = bl[col];
            vc[n] = v[col];
        }
        #pragma unroll
        for (int m = 0; m < 4; ++m) {
            float rp[4] = {0.f, 0.f, 0.f, 0.f};
            #pragma unroll
            for (int n = 0; n < 4; ++n)
                #pragma unroll
                for (int reg = 0; reg < 4; ++reg)
                    rp[reg] = fmaf(fmaxf(acc[m][n][reg] + blc[n], 0.f), vc[n], rp[reg]);
            #pragma unroll
            for (int reg = 0; reg < 4; ++reg) {
                float p = rp[reg];
                p += __shfl_xor(p, 1);
                p += __shfl_xor(p, 2);
                p += __shfl_xor(p, 4);
                p += __shfl_xor(p, 8);
                if (lr == 0)
                    red[wc][wr * 64 + m * 16 + (lane >> 4) * 4 + reg] = p;
            }
        }
        __syncthreads();
        if (tid < 128) {
            int row = row0 + tid;
            if (row < nrows) {
                float s = red[0][tid] + red[1][tid];
                if (MODE == 1) out[row] = cptr[0] + s;
                else out[row] += s;
            }
        }
    }
}

// ---------------------------------------------------------------------------
extern "C" void kernel_launch(void* const* d_in, const int* in_sizes, int n_in,
                              void* d_out, int out_size, void* d_ws, size_t ws_size,
                              hipStream_t stream) {
    const float* x_user = (const float*)d_in[0];
    const float* x_item = (const float*)d_in[1];
    const int* ei_m0_h0 = (const int*)d_in[2];
    const int* ei_m0_h1 = (const int*)d_in[3];
    const int* ei_m1_h0 = (const int*)d_in[4];
    const int* ei_m1_h1 = (const int*)d_in[5];
    const float* Wl00 = (const float*)d_in[6];
    const float* Wr00 = (const float*)d_in[7];
    const float* Wl01 = (const float*)d_in[8];
    const float* Wr01 = (const float*)d_in[9];
    const float* Wl10 = (const float*)d_in[10];
    const float* Wr10 = (const float*)d_in[11];
    const float* Wl11 = (const float*)d_in[12];
    const float* Wr11 = (const float*)d_in[13];
    const float* outW0 = (const float*)d_in[14];
    const float* outW1 = (const float*)d_in[15];
    const float* bl00 = (const float*)d_in[16];
    const float* bl01 = (const float*)d_in[17];
    const float* bl10 = (const float*)d_in[18];
    const float* bl11 = (const float*)d_in[19];
    const float* outb0 = (const float*)d_in[20];
    const float* outb1 = (const float*)d_in[21];
    const float* regW = (const float*)d_in[22];
    const float* regb = (const float*)d_in[23];

    const int N = in_sizes[0] / DIM;
    const int E = in_sizes[2] / 2;
    float* out = (float*)d_out;

    // ws: xbu | xbi | meanb | hib (bf16 N*128 each) | Wcat | vbuf |
    //     bpad | breal | bbase | rowptr[4N+1] | eidx[4E]
    // pairs (uint, 4*nbuck*PAIRC*4B = 25.6MB) ALIASES meanb: pairs die at
    // fillb; meanb first written by hop0 aggregate (stream-ordered, safe).
    const int n4 = 4 * N;
    const int nbuck = (N + 255) >> 8;
    ushort_t* xbu = (ushort_t*)d_ws;
    ushort_t* xbi = xbu + (size_t)N * DIM;
    ushort_t* meanb = xbi + (size_t)N * DIM;
    ushort_t* hib = meanb + (size_t)N * DIM;
    unsigned int* pairs = (unsigned int*)meanb;
    ushort_t* Wcat = hib + (size_t)N * DIM;
    float* vbuf = (float*)(Wcat + 4 * 32768);
    int* bpad = (int*)(vbuf + 2 * DIM + 1);
    int* breal = bpad + 4 * nbuck;
    int* bbase = breal + 4 * nbuck;
    int* rowptr = bbase + 4 * nbuck;
    int* eidx = rowptr + n4 + 1;

    // one-time conversions (merged launches)
    f32_to_bf16_2_kernel<<<dim3(1024, 2), 256, 0, stream>>>(x_user, x_item, xbu, xbi, N * DIM / 4);
    WPack wp;
    wp.Wl[0] = Wl00; wp.Wl[1] = Wl01; wp.Wl[2] = Wl10; wp.Wl[3] = Wl11;
    wp.Wr[0] = Wr00; wp.Wr[1] = Wr01; wp.Wr[2] = Wr10; wp.Wr[3] = Wr11;
    pack_weights4_kernel<<<dim3(128, 4), 256, 0, stream>>>(wp, Wcat);
    precompute_v_kernel<<<1, 256, 0, stream>>>(outW0, outW1, outb0, outb1, regW, regb, vbuf);

    // CSR build
    EdgePtrs eps;
    eps.e[0] = ei_m0_h0; eps.e[1] = ei_m0_h1; eps.e[2] = ei_m1_h0; eps.e[3] = ei_m1_h1;
    hipMemsetAsync(bpad, 0, (size_t)8 * nbuck * sizeof(int), stream);
    bin4_stage_kernel<<<dim3((E + CHUNK - 1) / CHUNK, 4), 512, 0, stream>>>(eps, E, bpad, breal, pairs, nbuck);
    bucket_scan_kernel<<<1, 512, 0, stream>>>(breal, bbase, 4 * nbuck, rowptr, n4, 4 * E);
    fillb_kernel<<<dim3(nbuck, 4), 256, 0, stream>>>(pairs, bpad, bbase, rowptr, eidx, N, nbuck);

    const int gemmBlocks = (N + 127) / 128;
    const int aggBlocks = 2048;

    struct Hop {
        const ushort_t* xsrc;
        const ushort_t* xdst;
        const ushort_t* W;
        const float* bl;
        int mode;
        const float* v;
    };
    const Hop hops[4] = {
        {xbu, xbi, Wcat + 0 * 32768, bl00, 0, nullptr},
        {hib, xbu, Wcat + 1 * 32768, bl01, 1, vbuf},
        {xbu, xbi, Wcat + 2 * 32768, bl10, 0, nullptr},
        {hib, xbu, Wcat + 3 * 32768, bl11, 2, vbuf + DIM},
    };

    for (int h = 0; h < 4; ++h) {
        const Hop& hp = hops[h];
        aggregate_kernel<<<aggBlocks, 256, 0, stream>>>(hp.xsrc, rowptr + (size_t)h * N, eidx, meanb, N);
        if (hp.mode == 0)
            sage_gemm_mfma<0><<<gemmBlocks, 256, 0, stream>>>(meanb, hp.xdst, hp.W, hp.bl,
                                                              hib, nullptr, nullptr, nullptr, N);
        else if (hp.mode == 1)
            sage_gemm_mfma<1><<<gemmBlocks, 256, 0, stream>>>(meanb, hp.xdst, hp.W, hp.bl,
                                                              nullptr, hp.v, vbuf + 2 * DIM, out, N);
        else
            sage_gemm_mfma<2><<<gemmBlocks, 256, 0, stream>>>(meanb, hp.xdst, hp.W, hp.bl,
                                                              nullptr, hp.v, vbuf + 2 * DIM, out, N);
    }
}

// Round 14
// 347.751 us; speedup vs baseline: 2.0393x; 1.0106x over previous
//
#include <hip/hip_runtime.h>

#define DIM 128
#define CHUNK 8192
#define PAIRC 4096
#define SENT 0xFFFFFFFFu
#define STAGECAP 14080   // CHUNK + 391*15 = 14057
typedef unsigned short ushort_t;
typedef short bf16x8 __attribute__((ext_vector_type(8)));
typedef float f32x4 __attribute__((ext_vector_type(4)));

__device__ inline ushort_t f2bf(float f) {
    unsigned int u = __float_as_uint(f);
    unsigned int r = (u + 0x7FFFu + ((u >> 16) & 1u)) >> 16;
    return (ushort_t)r;
}
__device__ inline unsigned int pack2bf(float lo, float hi) {
    return (unsigned int)f2bf(lo) | ((unsigned int)f2bf(hi) << 16);
}
__device__ inline float bflo2f(unsigned int u) { return __uint_as_float(u << 16); }
__device__ inline float bfhi2f(unsigned int u) { return __uint_as_float(u & 0xFFFF0000u); }
__device__ inline float2 unpk2(unsigned int u) { return make_float2(bflo2f(u), bfhi2f(u)); }

// ---------------------------------------------------------------------------
__global__ void f32_to_bf16_2_kernel(const float* __restrict__ a, const float* __restrict__ b,
                                     ushort_t* __restrict__ oa, ushort_t* __restrict__ ob, int n4) {
    const float* __restrict__ in = blockIdx.y ? b : a;
    ushort_t* __restrict__ out = blockIdx.y ? ob : oa;
    int i = blockIdx.x * blockDim.x + threadIdx.x;
    int stride = gridDim.x * blockDim.x;
    for (; i < n4; i += stride) {
        float4 v = *reinterpret_cast<const float4*>(in + (size_t)i * 4);
        ushort_t o[4] = {f2bf(v.x), f2bf(v.y), f2bf(v.z), f2bf(v.w)};
        *reinterpret_cast<uint2*>(out + (size_t)i * 4) = *reinterpret_cast<uint2*>(o);
    }
}

struct WPack { const float* Wl[4]; const float* Wr[4]; };

__global__ void pack_weights4_kernel(WPack wp, ushort_t* __restrict__ Wcat) {
    int l = blockIdx.y, j = blockIdx.x, k = threadIdx.x;
    float v = (k < DIM) ? wp.Wl[l][j * DIM + k] : wp.Wr[l][j * DIM + (k - DIM)];
    Wcat[l * 32768 + j * 256 + k] = f2bf(v);
}

// ---------------------------------------------------------------------------
__global__ void precompute_v_kernel(const float* __restrict__ outW0,
                                    const float* __restrict__ outW1,
                                    const float* __restrict__ outb0,
                                    const float* __restrict__ outb1,
                                    const float* __restrict__ regW,
                                    const float* __restrict__ regb,
                                    float* __restrict__ vbuf) {
    int t = threadIdx.x;
    if (t < DIM) {
        float s = 0.f;
        #pragma unroll 8
        for (int j = 0; j < DIM; ++j) s = fmaf(outW0[j * DIM + t], regW[j], s);
        vbuf[t] = s;
    } else {
        int k = t - DIM;
        float s = 0.f;
        #pragma unroll 8
        for (int j = 0; j < DIM; ++j) s = fmaf(outW1[j * DIM + k], regW[DIM + j], s);
        vbuf[t] = s;
    }
    if (t == 0) {
        float c = regb[0];
        for (int j = 0; j < DIM; ++j) c += outb0[j] * regW[j] + outb1[j] * regW[DIM + j];
        vbuf[2 * DIM] = c;
    }
}

// ---------------------------------------------------------------------------
// CSR build. pairs PACKED: (src<<8)|(dst&255), padded to 16-entry (64B) units.
// bin4_stage (512 threads): bin the chunk in LDS, then write each bucket
// region as FULL coalesced 64-lane bursts (single-writer-instruction lines).
// ---------------------------------------------------------------------------
struct EdgePtrs { const int* e[4]; };

__global__ void bin4_stage_kernel(EdgePtrs eps, int nedges, int* __restrict__ bpad,
                                  int* __restrict__ breal,
                                  unsigned int* __restrict__ pairs, int nbuck) {
    int list = blockIdx.y;
    const int* __restrict__ src = eps.e[list];
    const int* __restrict__ dst = eps.e[list] + nedges;
    __shared__ int cnt[512], loff[512], goff[512];
    __shared__ int wsum[8];
    __shared__ unsigned int stage[STAGECAP];
    const int tid = threadIdx.x;          // 512 threads = 8 waves
    const int lane = tid & 63, w = tid >> 6;
    const int base = blockIdx.x * CHUNK;

    if (tid < 512) cnt[tid] = 0;
    __syncthreads();

    // phase 1: count buckets (16 edges/thread)
    int dstv[CHUNK / 512];
    #pragma unroll
    for (int it = 0; it < CHUNK / 512; ++it) {
        int e = base + it * 512 + tid;
        int d = (e < nedges) ? dst[e] : -1;
        dstv[it] = d;
        if (d >= 0) atomicAdd(&cnt[d >> 8], 1);
    }
    __syncthreads();

    // phase 2a: exclusive scan of padded sizes -> loff (1 bucket/thread)
    {
        int c = cnt[tid];
        int r = (c + 15) & ~15;
        int sv = r;
        #pragma unroll
        for (int off = 1; off < 64; off <<= 1) {
            int u = __shfl_up(sv, off);
            if (lane >= off) sv += u;
        }
        if (lane == 63) wsum[w] = sv;
        __syncthreads();
        int bw = 0;
        #pragma unroll
        for (int k = 0; k < 8; ++k)
            if (k < w) bw += wsum[k];
        loff[tid] = bw + sv - r;
    }
    __syncthreads();
    // phase 2b: reserve global space per bucket; switch cnt to rank counter
    if (tid < nbuck) {
        int c = cnt[tid];
        int res = (c + 15) & ~15;
        if (res > 0) {
            goff[tid] = atomicAdd(&bpad[list * nbuck + tid], res);
            atomicAdd(&breal[list * nbuck + tid], c);
        }
        cnt[tid] = 0;
    }
    __syncthreads();

    // phase 3: scatter pairs into LDS stage (cnt returns to real count)
    #pragma unroll
    for (int it = 0; it < CHUNK / 512; ++it) {
        int d = dstv[it];
        if (d >= 0) {
            int e = base + it * 512 + tid;
            int r = atomicAdd(&cnt[d >> 8], 1);
            stage[loff[d >> 8] + r] = ((unsigned int)src[e] << 8) | (unsigned int)(d & 255);
        }
    }
    __syncthreads();

    // phase 4: burst copy-out, one bucket per wave iteration (sentinel tail inline)
    for (int b = w; b < nbuck; b += 8) {
        int c = cnt[b];
        int res = (c + 15) & ~15;
        if (res == 0) continue;
        size_t go = ((size_t)list * nbuck + b) * PAIRC + goff[b];
        int lo = loff[b];
        for (int i = lane; i < res; i += 64)
            pairs[go + i] = (i < c) ? stage[lo + i] : SENT;
    }
}

// single block, 512 threads, 4 elems/thread; n = 4*nbuck <= 2048 (scans breal)
__global__ void bucket_scan_kernel(const int* __restrict__ breal, int* __restrict__ bbase,
                                   int n, int* __restrict__ rowptr, int n4, int total) {
    int t = threadIdx.x;
    int loc[4];
    int s = 0;
    #pragma unroll
    for (int k = 0; k < 4; ++k) {
        int i = t * 4 + k;
        loc[k] = (i < n) ? breal[i] : 0;
        s += loc[k];
    }
    int lane = t & 63, w = t >> 6;
    int sv = s;
    #pragma unroll
    for (int off = 1; off < 64; off <<= 1) {
        int u = __shfl_up(sv, off);
        if (lane >= off) sv += u;
    }
    __shared__ int wsum[8];
    if (lane == 63) wsum[w] = sv;
    __syncthreads();
    int base = 0;
    #pragma unroll
    for (int k = 0; k < 8; ++k)
        if (k < w) base += wsum[k];
    int ex = base + sv - s;
    #pragma unroll
    for (int k = 0; k < 4; ++k) {
        int i = t * 4 + k;
        if (i < n) bbase[i] = ex;
        ex += loc[k];
    }
    if (t == 0) rowptr[n4] = total;
}

// one block per (bucket, list): skip sentinels, LDS histogram + scan,
// coalesced rowptr write, LDS-cursor placement into tight eidx region.
__global__ void fillb_kernel(const unsigned int* __restrict__ pairs, const int* __restrict__ bpad,
                             const int* __restrict__ bbase, int* __restrict__ rowptr,
                             int* __restrict__ eidx, int N, int nbuck) {
    int list = blockIdx.y;
    int b = blockIdx.x;
    int d0 = b << 8;
    if (d0 >= N) return;
    int nd = N - d0; if (nd > 256) nd = 256;
    int slot = list * nbuck + b;
    int cntp = bpad[slot];
    int base = bbase[slot];
    const unsigned int* __restrict__ ps = pairs + (size_t)slot * PAIRC;

    __shared__ int h[256], cur[256];
    int t = threadIdx.x;
    h[t] = 0;
    __syncthreads();
    for (int i = t; i < cntp; i += 256) {
        unsigned int p = ps[i];
        if (p != SENT) atomicAdd(&h[p & 255u], 1);
    }
    __syncthreads();
    int v = h[t];
    int lane = t & 63, w = t >> 6;
    int sv = v;
    #pragma unroll
    for (int off = 1; off < 64; off <<= 1) {
        int u = __shfl_up(sv, off);
        if (lane >= off) sv += u;
    }
    __shared__ int wsum[4];
    if (lane == 63) wsum[w] = sv;
    __syncthreads();
    int wbase = 0;
    #pragma unroll
    for (int k = 0; k < 4; ++k)
        if (k < w) wbase += wsum[k];
    int ex = wbase + sv - v;
    if (t < nd) rowptr[(size_t)list * N + d0 + t] = base + ex;
    cur[t] = ex;
    __syncthreads();
    for (int i = t; i < cntp; i += 256) {
        unsigned int p = ps[i];
        if (p != SENT) {
            int ld = (int)(p & 255u);
            int r = atomicAdd(&cur[ld], 1);
            eidx[base + r] = (int)(p >> 8);
        }
    }
}

// ---------------------------------------------------------------------------
// Gather-side mean, 4-edge MLP: one wave per row; sub-group s (16 lanes, uint4
// = 16B = 8 bf16 per lane) handles edges j = beg + it*4 + s. float2 accum
// nudges compiler toward v_pk_add_f32.
// ---------------------------------------------------------------------------
__global__ void aggregate_kernel(const ushort_t* __restrict__ xsrc,
                                 const int* __restrict__ rowptr,
                                 const int* __restrict__ eidx,
                                 ushort_t* __restrict__ mean, int n) {
    int wid = (blockIdx.x * blockDim.x + threadIdx.x) >> 6;
    int lane = threadIdx.x & 63;
    int nw = (gridDim.x * blockDim.x) >> 6;
    const int sub = lane >> 4;
    const int lr = lane & 15;
    for (int r = wid; r < n; r += nw) {
        int beg = rowptr[r];
        int end = rowptr[r + 1];
        int deg = end - beg;
        float2 a[4];
        #pragma unroll
        for (int k = 0; k < 4; ++k) a[k] = make_float2(0.f, 0.f);
        int nit = (deg + 3) >> 2;
        for (int it = 0; it < nit; ++it) {
            int j = beg + it * 4 + sub;
            if (j < end) {
                int s = eidx[j];
                uint4 u = *reinterpret_cast<const uint4*>(xsrc + (size_t)s * DIM + lr * 8);
                float2 p0 = unpk2(u.x), p1 = unpk2(u.y), p2 = unpk2(u.z), p3 = unpk2(u.w);
                a[0].x += p0.x; a[0].y += p0.y;
                a[1].x += p1.x; a[1].y += p1.y;
                a[2].x += p2.x; a[2].y += p2.y;
                a[3].x += p3.x; a[3].y += p3.y;
            }
        }
        #pragma unroll
        for (int k = 0; k < 4; ++k) {
            a[k].x += __shfl_xor(a[k].x, 16);
            a[k].y += __shfl_xor(a[k].y, 16);
            a[k].x += __shfl_xor(a[k].x, 32);
            a[k].y += __shfl_xor(a[k].y, 32);
        }
        if (sub == 0) {
            float sc = 1.0f / fmaxf((float)deg, 1.0f);
            uint4 o;
            o.x = pack2bf(a[0].x * sc, a[0].y * sc);
            o.y = pack2bf(a[1].x * sc, a[1].y * sc);
            o.z = pack2bf(a[2].x * sc, a[2].y * sc);
            o.w = pack2bf(a[3].x * sc, a[3].y * sc);
            *reinterpret_cast<uint4*>(mean + (size_t)r * DIM + lr * 8) = o;
        }
    }
}

// ---------------------------------------------------------------------------
// MFMA SAGE hop GEMM (bf16 in, f32 accum). Memory-bound: 4 blocks/CU for TLP
// (LDS 33.8KB x4 = 135KB < 160KB; VGPR cap 128 at 4 waves/EU).
// ---------------------------------------------------------------------------
template <int MODE>
__launch_bounds__(256, 4)
__global__ void sage_gemm_mfma(const ushort_t* __restrict__ A0,
                               const ushort_t* __restrict__ A1,
                               const ushort_t* __restrict__ Wcat,
                               const float* __restrict__ bl,
                               ushort_t* __restrict__ H,
                               const float* __restrict__ v,
                               const float* __restrict__ cptr,
                               float* __restrict__ out,
                               int nrows) {
    __shared__ ushort_t As[128][40];
    __shared__ ushort_t Bs[128][40];
    __shared__ float red[2][128];

    const int tid = threadIdx.x;
    const int lane = tid & 63;
    const int w = tid >> 6;
    const int wr = w >> 1, wc = w & 1;
    const int lr = lane & 15;
    const int lk = (lane >> 4) * 8;
    const int row0 = blockIdx.x * 128;

    f32x4 acc[4][4];
    #pragma unroll
    for (int m = 0; m < 4; ++m)
        #pragma unroll
        for (int n = 0; n < 4; ++n)
            acc[m][n] = (f32x4){0.f, 0.f, 0.f, 0.f};

    for (int kt = 0; kt < 8; ++kt) {
        const int kb = kt * 32;
        const ushort_t* __restrict__ Asrc = (kb < DIM) ? A0 : A1;
        const int kbb = kb & (DIM - 1);

        #pragma unroll
        for (int p = 0; p < 2; ++p) {
            int idx = p * 256 + tid;
            int r = idx >> 2, c = idx & 3;
            int grow = row0 + r;
            uint4 val = make_uint4(0u, 0u, 0u, 0u);
            if (grow < nrows)
                val = *reinterpret_cast<const uint4*>(Asrc + (size_t)grow * DIM + kbb + c * 8);
            *reinterpret_cast<uint4*>(&As[r][c * 8]) = val;
        }
        #pragma unroll
        for (int p = 0; p < 2; ++p) {
            int idx = p * 256 + tid;
            int j = idx >> 2, c = idx & 3;
            uint4 val = *reinterpret_cast<const uint4*>(Wcat + j * 256 + kb + c * 8);
            *reinterpret_cast<uint4*>(&Bs[j][c * 8]) = val;
        }
        __syncthreads();

        bf16x8 af[4], bfm[4];
        #pragma unroll
        for (int m = 0; m < 4; ++m)
            af[m] = *reinterpret_cast<const bf16x8*>(&As[wr * 64 + m * 16 + lr][lk]);
        #pragma unroll
        for (int n = 0; n < 4; ++n)
            bfm[n] = *reinterpret_cast<const bf16x8*>(&Bs[wc * 64 + n * 16 + lr][lk]);
        #pragma unroll
        for (int m = 0; m < 4; ++m)
            #pragma unroll
            for (int n = 0; n < 4; ++n)
                acc[m][n] = __builtin_amdgcn_mfma_f32_16x16x32_bf16(af[m], bfm[n], acc[m][n], 0, 0, 0);
        __syncthreads();
    }

    if (MODE == 0) {
        float blc[4];
        #pragma unroll
        for (int n = 0; n < 4; ++n) blc[n] = bl[wc * 64 + n * 16 + lr];
        #pragma unroll
        for (int m = 0; m < 4; ++m) {
            #pragma unroll
            for (int reg = 0; reg < 4; ++reg) {
                int row = row0 + wr * 64 + m * 16 + (lane >> 4) * 4 + reg;
                if (row < nrows) {
                    #pragma unroll
                    for (int n = 0; n < 4; ++n) {
                        int col = wc * 64 + n * 16 + lr;
                        H[(size_t)row * DIM + col] = f2bf(fmaxf(acc[m][n][reg] + blc[n], 0.f));
                    }
                }
            }
        }
    } else {
        float blc[4], vc[4];
        #pragma unroll
        for (int n = 0; n < 4; ++n) {
            int col = wc * 64 + n * 16 + lr;
            blc[n] = bl[col];
            vc[n] = v[col];
        }
        #pragma unroll
        for (int m = 0; m < 4; ++m) {
            float rp[4] = {0.f, 0.f, 0.f, 0.f};
            #pragma unroll
            for (int n = 0; n < 4; ++n)
                #pragma unroll
                for (int reg = 0; reg < 4; ++reg)
                    rp[reg] = fmaf(fmaxf(acc[m][n][reg] + blc[n], 0.f), vc[n], rp[reg]);
            #pragma unroll
            for (int reg = 0; reg < 4; ++reg) {
                float p = rp[reg];
                p += __shfl_xor(p, 1);
                p += __shfl_xor(p, 2);
                p += __shfl_xor(p, 4);
                p += __shfl_xor(p, 8);
                if (lr == 0)
                    red[wc][wr * 64 + m * 16 + (lane >> 4) * 4 + reg] = p;
            }
        }
        __syncthreads();
        if (tid < 128) {
            int row = row0 + tid;
            if (row < nrows) {
                float s = red[0][tid] + red[1][tid];
                if (MODE == 1) out[row] = cptr[0] + s;
                else out[row] += s;
            }
        }
    }
}

// ---------------------------------------------------------------------------
extern "C" void kernel_launch(void* const* d_in, const int* in_sizes, int n_in,
                              void* d_out, int out_size, void* d_ws, size_t ws_size,
                              hipStream_t stream) {
    const float* x_user = (const float*)d_in[0];
    const float* x_item = (const float*)d_in[1];
    const int* ei_m0_h0 = (const int*)d_in[2];
    const int* ei_m0_h1 = (const int*)d_in[3];
    const int* ei_m1_h0 = (const int*)d_in[4];
    const int* ei_m1_h1 = (const int*)d_in[5];
    const float* Wl00 = (const float*)d_in[6];
    const float* Wr00 = (const float*)d_in[7];
    const float* Wl01 = (const float*)d_in[8];
    const float* Wr01 = (const float*)d_in[9];
    const float* Wl10 = (const float*)d_in[10];
    const float* Wr10 = (const float*)d_in[11];
    const float* Wl11 = (const float*)d_in[12];
    const float* Wr11 = (const float*)d_in[13];
    const float* outW0 = (const float*)d_in[14];
    const float* outW1 = (const float*)d_in[15];
    const float* bl00 = (const float*)d_in[16];
    const float* bl01 = (const float*)d_in[17];
    const float* bl10 = (const float*)d_in[18];
    const float* bl11 = (const float*)d_in[19];
    const float* outb0 = (const float*)d_in[20];
    const float* outb1 = (const float*)d_in[21];
    const float* regW = (const float*)d_in[22];
    const float* regb = (const float*)d_in[23];

    const int N = in_sizes[0] / DIM;
    const int E = in_sizes[2] / 2;
    float* out = (float*)d_out;

    // ws: xbu | xbi | meanb | hib (bf16 N*128 each) | Wcat | vbuf |
    //     bpad | breal | bbase | rowptr[4N+1] | eidx[4E]
    // pairs (uint, 4*nbuck*PAIRC*4B = 25.6MB) ALIASES meanb: pairs die at
    // fillb; meanb first written by hop0 aggregate (stream-ordered, safe).
    const int n4 = 4 * N;
    const int nbuck = (N + 255) >> 8;
    ushort_t* xbu = (ushort_t*)d_ws;
    ushort_t* xbi = xbu + (size_t)N * DIM;
    ushort_t* meanb = xbi + (size_t)N * DIM;
    ushort_t* hib = meanb + (size_t)N * DIM;
    unsigned int* pairs = (unsigned int*)meanb;
    ushort_t* Wcat = hib + (size_t)N * DIM;
    float* vbuf = (float*)(Wcat + 4 * 32768);
    int* bpad = (int*)(vbuf + 2 * DIM + 1);
    int* breal = bpad + 4 * nbuck;
    int* bbase = breal + 4 * nbuck;
    int* rowptr = bbase + 4 * nbuck;
    int* eidx = rowptr + n4 + 1;

    // one-time conversions (merged launches)
    f32_to_bf16_2_kernel<<<dim3(1024, 2), 256, 0, stream>>>(x_user, x_item, xbu, xbi, N * DIM / 4);
    WPack wp;
    wp.Wl[0] = Wl00; wp.Wl[1] = Wl01; wp.Wl[2] = Wl10; wp.Wl[3] = Wl11;
    wp.Wr[0] = Wr00; wp.Wr[1] = Wr01; wp.Wr[2] = Wr10; wp.Wr[3] = Wr11;
    pack_weights4_kernel<<<dim3(128, 4), 256, 0, stream>>>(wp, Wcat);
    precompute_v_kernel<<<1, 256, 0, stream>>>(outW0, outW1, outb0, outb1, regW, regb, vbuf);

    // CSR build
    EdgePtrs eps;
    eps.e[0] = ei_m0_h0; eps.e[1] = ei_m0_h1; eps.e[2] = ei_m1_h0; eps.e[3] = ei_m1_h1;
    hipMemsetAsync(bpad, 0, (size_t)8 * nbuck * sizeof(int), stream);
    bin4_stage_kernel<<<dim3((E + CHUNK - 1) / CHUNK, 4), 512, 0, stream>>>(eps, E, bpad, breal, pairs, nbuck);
    bucket_scan_kernel<<<1, 512, 0, stream>>>(breal, bbase, 4 * nbuck, rowptr, n4, 4 * E);
    fillb_kernel<<<dim3(nbuck, 4), 256, 0, stream>>>(pairs, bpad, bbase, rowptr, eidx, N, nbuck);

    const int gemmBlocks = (N + 127) / 128;
    const int aggBlocks = 2048;

    struct Hop {
        const ushort_t* xsrc;
        const ushort_t* xdst;
        const ushort_t* W;
        const float* bl;
        int mode;
        const float* v;
    };
    const Hop hops[4] = {
        {xbu, xbi, Wcat + 0 * 32768, bl00, 0, nullptr},
        {hib, xbu, Wcat + 1 * 32768, bl01, 1, vbuf},
        {xbu, xbi, Wcat + 2 * 32768, bl10, 0, nullptr},
        {hib, xbu, Wcat + 3 * 32768, bl11, 2, vbuf + DIM},
    };

    for (int h = 0; h < 4; ++h) {
        const Hop& hp = hops[h];
        aggregate_kernel<<<aggBlocks, 256, 0, stream>>>(hp.xsrc, rowptr + (size_t)h * N, eidx, meanb, N);
        if (hp.mode == 0)
            sage_gemm_mfma<0><<<gemmBlocks, 256, 0, stream>>>(meanb, hp.xdst, hp.W, hp.bl,
                                                              hib, nullptr, nullptr, nullptr, N);
        else if (hp.mode == 1)
            sage_gemm_mfma<1><<<gemmBlocks, 256, 0, stream>>>(meanb, hp.xdst, hp.W, hp.bl,
                                                              nullptr, hp.v, vbuf + 2 * DIM, out, N);
        else
            sage_gemm_mfma<2><<<gemmBlocks, 256, 0, stream>>>(meanb, hp.xdst, hp.W, hp.bl,
                                                              nullptr, hp.v, vbuf + 2 * DIM, out, N);
    }
}